// Round 19
// baseline (2114.535 us; speedup 1.0000x reference)
//
#include <hip/hip_runtime.h>
#include <math.h>

#define N_ 2048
#define R_ 64
#define D_ 64
#define K_ 512
#define M_ (N_*R_)      // 131072 rows
#define TAU 0.012f      // gap threshold; split-bf16 score err <= ~5e-4 << TAU/2
#define CHK 0.012f      // winner exact-vs-approx verification threshold

// ws float offsets / byte layout:
// [0] vq acc | [16..527] wn | [1024..5119] gram |
// byte 32768: whi fragment-ordered (64KB) | byte 98304: wlo (64KB)
#define WN_OFF   16
#define GRAM_OFF 1024
#define WBF_BYTE 32768
#define WS_NEED  163840

typedef __attribute__((ext_vector_type(8))) short s16x8;
typedef __attribute__((ext_vector_type(4))) float f32x4;

static __device__ __forceinline__ unsigned short f2bf(float f) {
    unsigned u = __float_as_uint(f);
    u += 0x7FFFu + ((u >> 16) & 1u);
    return (unsigned short)(u >> 16);
}
static __device__ __forceinline__ float bf2f(unsigned short h) {
    return __uint_as_float(((unsigned)h) << 16);
}

// 128-row x-tile LDS addressing: row r (0..127), float4-granule q (0..15), swizzled
static __device__ __forceinline__ int xs_byte(int r, int q) {
    return r * 256 + (q >> 3) * 128 + (((q & 7) ^ (r & 7)) * 16);
}

static __device__ __forceinline__ void split8(const float* vv, s16x8& ph, s16x8& pl) {
#pragma unroll
    for (int j = 0; j < 8; ++j) {
        const unsigned short hb = f2bf(vv[j]);
        ph[j] = (short)hb;
        pl[j] = (short)f2bf(vv[j] - bf2f(hb));
    }
}

static __device__ __forceinline__ void nt_store4(float* p, float x0, float x1, float x2, float x3) {
    f32x4 v = {x0, x1, x2, x3};
    __builtin_nontemporal_store(v, (f32x4*)p);
}

// ---------------- k_pre: gram (b<64) | wn + zero acc (b 64-65) | W fragment-ordered split (b 66-67)
__global__ void k_pre(const float* __restrict__ w, float* __restrict__ ws, int pre) {
    const int b = blockIdx.x, t = threadIdx.x;
    if (b < 64) {
        __shared__ float red[4][64];
        const int i = b, j = t & 63, kg = t >> 6;
        float s = 0.f;
        for (int k = kg * 128; k < kg * 128 + 128; ++k)
            s = fmaf(w[k * 64 + i], w[k * 64 + j], s);
        red[kg][j] = s;
        __syncthreads();
        if (t < 64)
            ws[GRAM_OFF + i * 64 + t] = red[0][t] + red[1][t] + red[2][t] + red[3][t];
    } else if (b < 66) {
        const int code = (b - 64) * 256 + t;
        const float4* wr = (const float4*)(w + code * 64);
        float s = 0.f;
#pragma unroll
        for (int i = 0; i < 16; ++i) {
            float4 v = wr[i];
            s += v.x * v.x + v.y * v.y + v.z * v.z + v.w * v.w;
        }
        ws[WN_OFF + code] = s;
        if (b == 64 && t == 0) ws[0] = 0.f;
    } else {
        if (!pre) return;
        const int code = (b - 66) * 256 + t;   // 512 codes
        char* whi = (char*)ws + WBF_BYTE;
        char* wlo = whi + 65536;
        const int c = code >> 6, rr = code & 63;
        const int nt = rr >> 4, lr = rr & 15;
        for (int kg = 0; kg < 8; ++kg) {
            float4 v0 = *(const float4*)(w + code * 64 + kg * 8);
            float4 v1 = *(const float4*)(w + code * 64 + kg * 8 + 4);
            const float vv[8] = {v0.x, v0.y, v0.z, v0.w, v1.x, v1.y, v1.z, v1.w};
            s16x8 ph, pl;
            split8(vv, ph, pl);
            const int s = kg >> 2, g = kg & 3, l = g * 16 + lr;
            const int off = (((c * 2 + s) * 4 + nt) << 10) + l * 16;  // FRAG(c,s,nt) + lane*16
            *(s16x8*)(whi + off) = ph;
            *(s16x8*)(wlo + off) = pl;
        }
    }
}

// ================ shared kernel body (PH: 1=stage+Afrag, 2=+score, 3=+verify/fix, 4=full)
template<int PH, bool PRE>
__device__ __forceinline__ void argmin_body(
    const float* __restrict__ x, const float* __restrict__ w,
    float* __restrict__ ws, float* __restrict__ out, int dumpoff)
{
    __shared__ __align__(16) float xs[8192];
    __shared__ __align__(16) float redw[2][4][64];
    __shared__ float fb1[128], fb2[128];
    __shared__ int   ridx[128];
    __shared__ int   ulist[128];
    __shared__ int   nunc;

    const int t = threadIdx.x;
    const int l = t & 63, wid = t >> 6;
    const int g = l >> 4, lr = l & 15;
    const long brow = (long)blockIdx.x * 128;
    const float* wn_g = ws + WN_OFF;
    const char* whi = (const char*)ws + WBF_BYTE;
    const char* wlo = whi + 65536;

    if (t == 0) nunc = 0;

    s16x8 pbh[2][4], pbl[2][4];
    float4 pv0[2][4], pv1[2][4];
    f32x4 acc[2][4];

    auto issue = [&](int h, int par) {
        const int c = h >> 1, half = h & 1;
#pragma unroll
        for (int s = 0; s < 2; ++s)
#pragma unroll
            for (int nth = 0; nth < 2; ++nth) {
                const int nt = half * 2 + nth, idx = s * 2 + nth;
                if constexpr (PRE) {
                    const int off = (((c * 2 + s) * 4 + nt) << 10) + l * 16;
                    pbh[par][idx] = *(const s16x8*)(whi + off);
                    pbl[par][idx] = *(const s16x8*)(wlo + off);
                } else {
                    const int crow = c * 64 + nt * 16 + lr;
                    const float* src = w + (long)crow * 64 + (s * 4 + g) * 8;
                    pv0[par][idx] = *(const float4*)src;
                    pv1[par][idx] = *(const float4*)(src + 4);
                }
            }
    };

    issue(0, 0);

    // ---- stage x-tile
#pragma unroll
    for (int ii = 0; ii < 8; ++ii) {
        const int gid = ii * 256 + t;
        const int r = gid >> 4, qq = gid & 15;
        const float4 v = *(const float4*)(x + (brow + r) * 64 + qq * 4);
        *(float4*)((char*)xs + xs_byte(r, qq)) = v;
    }
    __syncthreads();

    // ---- A fragments
    s16x8 ah[2][2], al[2][2];
#pragma unroll
    for (int mt = 0; mt < 2; ++mt) {
        const int row = wid * 32 + mt * 16 + lr;
#pragma unroll
        for (int s = 0; s < 2; ++s) {
            const int kg = s * 4 + g;
            const float4 v0 = *(const float4*)((const char*)xs + xs_byte(row, kg * 2));
            const float4 v1 = *(const float4*)((const char*)xs + xs_byte(row, kg * 2 + 1));
            const float vv[8] = {v0.x, v0.y, v0.z, v0.w, v1.x, v1.y, v1.z, v1.w};
            split8(vv, ah[mt][s], al[mt][s]);
        }
    }

    if constexpr (PH == 1) {
        float v = 0.f;
#pragma unroll
        for (int mt = 0; mt < 2; ++mt)
#pragma unroll
            for (int s = 0; s < 2; ++s) {
                f32x4 a = *(f32x4*)&ah[mt][s];
                f32x4 b = *(f32x4*)&al[mt][s];
                v += a[0] + a[1] + a[2] + a[3] + b[0] + b[1] + b[2] + b[3];
            }
        ws[dumpoff + ((blockIdx.x * 256 + t) & 4095)] = v;
        return;
    }

    float b1[2][4], b2[2][4]; int i1[2][4];
#pragma unroll
    for (int mt = 0; mt < 2; ++mt)
#pragma unroll
        for (int j = 0; j < 4; ++j) { b1[mt][j] = 3.4e38f; b2[mt][j] = 3.4e38f; i1[mt][j] = 0; }

    auto compute = [&](int h, int par) {
        const int c = h >> 1, half = h & 1;
        if (half == 0) {
            const f32x4 z = {0.f, 0.f, 0.f, 0.f};
#pragma unroll
            for (int mt = 0; mt < 2; ++mt)
#pragma unroll
                for (int nt = 0; nt < 4; ++nt) acc[mt][nt] = z;
        }
#pragma unroll
        for (int s = 0; s < 2; ++s)
#pragma unroll
            for (int nth = 0; nth < 2; ++nth) {
                const int nt = half * 2 + nth, idx = s * 2 + nth;
                s16x8 BH, BL;
                if constexpr (PRE) {
                    BH = pbh[par][idx]; BL = pbl[par][idx];
                } else {
                    const float4 v0 = pv0[par][idx], v1 = pv1[par][idx];
                    const float vv[8] = {v0.x, v0.y, v0.z, v0.w, v1.x, v1.y, v1.z, v1.w};
                    split8(vv, BH, BL);
                }
#pragma unroll
                for (int mt = 0; mt < 2; ++mt) {
                    acc[mt][nt] = __builtin_amdgcn_mfma_f32_16x16x32_bf16(ah[mt][s], BH, acc[mt][nt], 0, 0, 0);
                    acc[mt][nt] = __builtin_amdgcn_mfma_f32_16x16x32_bf16(al[mt][s], BH, acc[mt][nt], 0, 0, 0);
                    acc[mt][nt] = __builtin_amdgcn_mfma_f32_16x16x32_bf16(ah[mt][s], BL, acc[mt][nt], 0, 0, 0);
                }
            }
        if (half == 1) {
#pragma unroll
            for (int nt = 0; nt < 4; ++nt) {
                const int code = c * 64 + nt * 16 + lr;
                const float wnv = wn_g[code];
#pragma unroll
                for (int mt = 0; mt < 2; ++mt)
#pragma unroll
                    for (int j = 0; j < 4; ++j) {
                        const float sv = fmaf(-2.f, acc[mt][nt][j], wnv);
                        if (sv < b1[mt][j]) { b2[mt][j] = b1[mt][j]; b1[mt][j] = sv; i1[mt][j] = code; }
                        else if (sv < b2[mt][j]) b2[mt][j] = sv;
                    }
            }
        }
    };

#pragma unroll
    for (int h = 0; h < 16; ++h) {
        if (h < 15) issue(h + 1, (h + 1) & 1);
        compute(h, h & 1);
    }

    // ---- cross-lane merge
#pragma unroll
    for (int m = 1; m < 16; m <<= 1) {
#pragma unroll
        for (int mt = 0; mt < 2; ++mt)
#pragma unroll
            for (int j = 0; j < 4; ++j) {
                const float ov1 = __shfl_xor(b1[mt][j], m, 64);
                const int   oi1 = __shfl_xor(i1[mt][j], m, 64);
                const float ov2 = __shfl_xor(b2[mt][j], m, 64);
                const float nb2 = fminf(fminf(b2[mt][j], ov2), fmaxf(b1[mt][j], ov1));
                if (ov1 < b1[mt][j] || (ov1 == b1[mt][j] && oi1 < i1[mt][j])) {
                    b1[mt][j] = ov1; i1[mt][j] = oi1;
                }
                b2[mt][j] = nb2;
            }
    }

    if constexpr (PH == 2) {
        float v = 0.f;
#pragma unroll
        for (int mt = 0; mt < 2; ++mt)
#pragma unroll
            for (int j = 0; j < 4; ++j)
                v += b1[mt][j] + b2[mt][j] + (float)i1[mt][j];
        ws[dumpoff + ((blockIdx.x * 256 + t) & 4095)] = v;
        return;
    }

    if (lr == 0) {
#pragma unroll
        for (int mt = 0; mt < 2; ++mt)
#pragma unroll
            for (int j = 0; j < 4; ++j) {
                const int ro = wid * 32 + mt * 16 + g * 4 + j;
                ridx[ro] = i1[mt][j];
                fb1[ro] = b1[mt][j];
                fb2[ro] = b2[mt][j];
            }
    }
    __syncthreads();

    // ---- winner verification
    {
        const int r = t >> 1, sub = t & 1;
        const int ci = ridx[r];
        const float* wrow = w + (long)ci * 64 + sub * 32;
        float dot = 0.f;
#pragma unroll
        for (int p = 0; p < 8; ++p) {
            const float4 xv = *(const float4*)((const char*)xs + xs_byte(r, sub * 8 + p));
            const float4 wv = *(const float4*)(wrow + p * 4);
            dot = fmaf(xv.x, wv.x, dot);
            dot = fmaf(xv.y, wv.y, dot);
            dot = fmaf(xv.z, wv.z, dot);
            dot = fmaf(xv.w, wv.w, dot);
        }
        dot += __shfl_xor(dot, 1, 64);
        if (sub == 0) {
            const float sex = fmaf(-2.f, dot, wn_g[ci]);
            const bool unc = ((fb2[r] - fb1[r]) < TAU) || (fabsf(sex - fb1[r]) > CHK);
            if (unc) { const int p = atomicAdd(&nunc, 1); ulist[p] = r; }
        }
    }
    __syncthreads();

    // ---- exact fix
    const int nu = nunc;
    if (nu > 0) {
        for (int e = wid; e < nu; e += 4) {
            const int r = ulist[e];
            float bv = 3.4e38f; int bi = 0;
            for (int cc = 0; cc < 8; ++cc) {
                const int code = cc * 64 + l;
                const float* wrow = w + (long)code * 64;
                float dot = 0.f;
#pragma unroll
                for (int p = 0; p < 16; ++p) {
                    const float4 xv = *(const float4*)((const char*)xs + xs_byte(r, p));
                    const float4 wv = *(const float4*)(wrow + p * 4);
                    dot = fmaf(xv.x, wv.x, dot);
                    dot = fmaf(xv.y, wv.y, dot);
                    dot = fmaf(xv.z, wv.z, dot);
                    dot = fmaf(xv.w, wv.w, dot);
                }
                const float sv = fmaf(-2.f, dot, wn_g[code]);
                if (sv < bv) { bv = sv; bi = code; }
            }
#pragma unroll
            for (int m = 1; m < 64; m <<= 1) {
                const float ov = __shfl_xor(bv, m, 64);
                const int   oi = __shfl_xor(bi, m, 64);
                if (ov < bv || (ov == bv && oi < bi)) { bv = ov; bi = oi; }
            }
            if (l == 0) ridx[r] = bi;
        }
    }
    __syncthreads();

    if constexpr (PH == 3) {
        ws[dumpoff + ((blockIdx.x * 256 + t) & 4095)] =
            (float)ridx[t & 127] + fb1[(t * 3) & 127];
        return;
    }

    // ---- epilogue (PH == 4 only)
    float* q_sg = out + 5;
    float* q    = out + 5 + (long)M_ * 64;
    float* fidx = out + 5 + 2L * M_ * 64;
    const int qq = t & 15, ry = t >> 4;
    float4 va = {0.f, 0.f, 0.f, 0.f}, vb = {0.f, 0.f, 0.f, 0.f};
#pragma unroll
    for (int ii = 0; ii < 8; ++ii) {
        const int r = ii * 16 + ry;
        const int ci = ridx[r];
        const float4 wv4 = *(const float4*)(w + (long)ci * 64 + qq * 4);
        const float4 xv4 = *(const float4*)((const char*)xs + xs_byte(r, qq));
        const long off = (brow + r) * 64 + qq * 4;
        nt_store4(q_sg + off, wv4.x, wv4.y, wv4.z, wv4.w);
        nt_store4(q + off,    wv4.x, wv4.y, wv4.z, wv4.w);
        float4 p;
        p.x = (wv4.x - xv4.x) * (wv4.x - xv4.x);
        p.y = (wv4.y - xv4.y) * (wv4.y - xv4.y);
        p.z = (wv4.z - xv4.z) * (wv4.z - xv4.z);
        p.w = (wv4.w - xv4.w) * (wv4.w - xv4.w);
        float4 p2;
        p2.x = p.x * p.x; p2.y = p.y * p.y; p2.z = p.z * p.z; p2.w = p.w * p.w;
        if (ii < 4) {
            va.x += p2.x; va.y += p2.y; va.z += p2.z; va.w += p2.w;
        } else {
            vb.x += p2.x; vb.y += p2.y; vb.z += p2.z; vb.w += p2.w;
        }
    }
#pragma unroll
    for (int m = 16; m < 64; m <<= 1) {
        va.x += __shfl_xor(va.x, m, 64); va.y += __shfl_xor(va.y, m, 64);
        va.z += __shfl_xor(va.z, m, 64); va.w += __shfl_xor(va.w, m, 64);
        vb.x += __shfl_xor(vb.x, m, 64); vb.y += __shfl_xor(vb.y, m, 64);
        vb.z += __shfl_xor(vb.z, m, 64); vb.w += __shfl_xor(vb.w, m, 64);
    }
    if (l < 16) {
        *(float4*)&redw[0][wid][l * 4] = va;
        *(float4*)&redw[1][wid][l * 4] = vb;
    }
    if (t < 128) __builtin_nontemporal_store((float)ridx[t], fidx + brow + t);
    __syncthreads();

    if (t < 128) {
        const int n = t >> 6, d = t & 63;
        const float s = redw[n][0][d] + redw[n][1][d] + redw[n][2][d] + redw[n][3][d];
        float v = sqrtf(s);
#pragma unroll
        for (int m = 1; m < 64; m <<= 1) v += __shfl_xor(v, m, 64);
        if (d == 0) atomicAdd(ws + 0, v);
    }
}

// ---------------- real kernel + ablation variants
template<bool PRE>
__global__ __launch_bounds__(256, 3) void k_argmin(
    const float* __restrict__ x, const float* __restrict__ w,
    float* __restrict__ ws, float* __restrict__ out)
{
    argmin_body<4, PRE>(x, w, ws, out, 0);
}

template<int PH, bool PRE>
__global__ __launch_bounds__(256, 3) void k_abl(
    const float* __restrict__ x, const float* __restrict__ w,
    float* __restrict__ ws, int dumpoff)
{
    argmin_body<PH, PRE>(x, w, ws, nullptr, dumpoff);
}

// ---------------- k_final: orth from gram, rank via Gaussian elimination (1 barrier/step)
__global__ void k_final(const float* __restrict__ ws, float* __restrict__ out)
{
    __shared__ float g[64][65];
    __shared__ float osum[4];
    __shared__ float tol;
    const int t = threadIdx.x;
    float oacc = 0.f;
    for (int i = t; i < 4096; i += 256) {
        const int r = i >> 6, cl = i & 63;
        const float gv = ws[GRAM_OFF + i];
        g[r][cl] = gv;
        const float p = gv - (r == cl ? 1.f : 0.f);
        oacc = fmaf(p, p, oacc);
    }
#pragma unroll
    for (int m = 1; m < 64; m <<= 1) oacc += __shfl_xor(oacc, m, 64);
    if ((t & 63) == 0) osum[t >> 6] = oacc;
    __syncthreads();

    if (t == 0) {
        float maxd = 0.f;
        for (int i = 0; i < 64; ++i) maxd = fmaxf(maxd, fabsf(g[i][i]));
        tol = maxd * 1e-7f + 1e-30f;
    }
    __syncthreads();

    int rank = 0;
    const int j = t & 63, rq = t >> 6;
    for (int s = 0; s < 64; ++s) {
        const float p = g[s][s];
        const bool ok = fabsf(p) > tol;
        if (ok) {
            rank++;
            if (j > s) {
                const float rp = 1.f / p;
                const float gsj = g[s][j];
                for (int r = s + 1 + rq; r < 64; r += 4)
                    g[r][j] = fmaf(-(g[r][s] * rp), gsj, g[r][j]);
            }
        }
        __syncthreads();
    }

    if (t == 0) {
        const float vq = ws[0] / (float)(N_ * D_);
        const float orth = sqrtf(osum[0] + osum[1] + osum[2] + osum[3]);
        out[0] = 1.5f * vq;
        out[1] = vq;
        out[2] = vq;
        out[3] = orth;
        out[4] = (float)rank;
    }
}

// ---------------- launcher
extern "C" void kernel_launch(void* const* d_in, const int* in_sizes, int n_in,
                              void* d_out, int out_size, void* d_ws, size_t ws_size,
                              hipStream_t stream) {
    const float* x = (const float*)d_in[0];   // soft_fillers [N,R,D]
    const float* w = (const float*)d_in[1];   // weight [K,D]
    float* out = (float*)d_out;
    float* ws  = (float*)d_ws;
    const int pre = (ws_size >= (size_t)WS_NEED) ? 1 : 0;
    const int dumpoff = pre ? (WBF_BYTE / 4) : GRAM_OFF;

    // ===== ablation probes (write ONLY to ws dump region; k_pre reinitializes after)
    if (pre) {
        hipLaunchKernelGGL((k_abl<1,true>),  dim3(1024), dim3(256), 0, stream, x, w, ws, dumpoff);
        hipLaunchKernelGGL((k_abl<2,true>),  dim3(1024), dim3(256), 0, stream, x, w, ws, dumpoff);
        hipLaunchKernelGGL((k_abl<2,false>), dim3(1024), dim3(256), 0, stream, x, w, ws, dumpoff);
        hipLaunchKernelGGL((k_abl<3,true>),  dim3(1024), dim3(256), 0, stream, x, w, ws, dumpoff);
    } else {
        hipLaunchKernelGGL((k_abl<1,false>), dim3(1024), dim3(256), 0, stream, x, w, ws, dumpoff);
        hipLaunchKernelGGL((k_abl<2,false>), dim3(1024), dim3(256), 0, stream, x, w, ws, dumpoff);
        hipLaunchKernelGGL((k_abl<3,false>), dim3(1024), dim3(256), 0, stream, x, w, ws, dumpoff);
    }

    // ===== real pipeline (identical to R18)
    hipLaunchKernelGGL(k_pre, dim3(68), dim3(256), 0, stream, w, ws, pre);
    if (pre)
        hipLaunchKernelGGL((k_argmin<true>),  dim3(1024), dim3(256), 0, stream, x, w, ws, out);
    else
        hipLaunchKernelGGL((k_argmin<false>), dim3(1024), dim3(256), 0, stream, x, w, ws, out);
    hipLaunchKernelGGL(k_final, dim3(1), dim3(256), 0, stream, ws, out);
}

// Round 20
// 155.024 us; speedup vs baseline: 13.6401x; 13.6401x over previous
//
#include <hip/hip_runtime.h>
#include <math.h>

#define N_ 2048
#define R_ 64
#define D_ 64
#define K_ 512
#define M_ (N_*R_)      // 131072 rows
#define TAU 0.012f      // gap threshold; split-bf16 score err <= ~5e-4 << TAU/2
#define CHK 0.012f      // winner exact-vs-approx verification threshold

// ws float offsets / byte layout:
// [0] vq acc | [16..527] wn | [1024..5119] gram |
// byte 32768: whi fragment-ordered (64KB) | byte 98304: wlo (64KB)
#define WN_OFF   16
#define GRAM_OFF 1024
#define WBF_BYTE 32768
#define WS_NEED  163840

typedef __attribute__((ext_vector_type(8))) short s16x8;
typedef __attribute__((ext_vector_type(4))) float f32x4;

static __device__ __forceinline__ unsigned short f2bf(float f) {
    unsigned u = __float_as_uint(f);
    u += 0x7FFFu + ((u >> 16) & 1u);
    return (unsigned short)(u >> 16);
}
static __device__ __forceinline__ float bf2f(unsigned short h) {
    return __uint_as_float(((unsigned)h) << 16);
}

// 128-row x-tile LDS addressing: row r (0..127), float4-granule q (0..15), swizzled
static __device__ __forceinline__ int xs_byte(int r, int q) {
    return r * 256 + (q >> 3) * 128 + (((q & 7) ^ (r & 7)) * 16);
}

static __device__ __forceinline__ void split8(const float* vv, s16x8& ph, s16x8& pl) {
#pragma unroll
    for (int j = 0; j < 8; ++j) {
        const unsigned short hb = f2bf(vv[j]);
        ph[j] = (short)hb;
        pl[j] = (short)f2bf(vv[j] - bf2f(hb));
    }
}

static __device__ __forceinline__ void nt_store4(float* p, float x0, float x1, float x2, float x3) {
    f32x4 v = {x0, x1, x2, x3};
    __builtin_nontemporal_store(v, (f32x4*)p);
}

// ---------------- k_pre: gram (b<64) | wn + zero acc (b 64-65) | W fragment-ordered split (b 66-67)
__global__ void k_pre(const float* __restrict__ w, float* __restrict__ ws, int pre) {
    const int b = blockIdx.x, t = threadIdx.x;
    if (b < 64) {
        __shared__ float red[4][64];
        const int i = b, j = t & 63, kg = t >> 6;
        float s = 0.f;
        for (int k = kg * 128; k < kg * 128 + 128; ++k)
            s = fmaf(w[k * 64 + i], w[k * 64 + j], s);
        red[kg][j] = s;
        __syncthreads();
        if (t < 64)
            ws[GRAM_OFF + i * 64 + t] = red[0][t] + red[1][t] + red[2][t] + red[3][t];
    } else if (b < 66) {
        const int code = (b - 64) * 256 + t;
        const float4* wr = (const float4*)(w + code * 64);
        float s = 0.f;
#pragma unroll
        for (int i = 0; i < 16; ++i) {
            float4 v = wr[i];
            s += v.x * v.x + v.y * v.y + v.z * v.z + v.w * v.w;
        }
        ws[WN_OFF + code] = s;
        if (b == 64 && t == 0) ws[0] = 0.f;
    } else {
        if (!pre) return;
        const int code = (b - 66) * 256 + t;   // 512 codes
        char* whi = (char*)ws + WBF_BYTE;
        char* wlo = whi + 65536;
        const int c = code >> 6, rr = code & 63;
        const int nt = rr >> 4, lr = rr & 15;
        for (int kg = 0; kg < 8; ++kg) {
            float4 v0 = *(const float4*)(w + code * 64 + kg * 8);
            float4 v1 = *(const float4*)(w + code * 64 + kg * 8 + 4);
            const float vv[8] = {v0.x, v0.y, v0.z, v0.w, v1.x, v1.y, v1.z, v1.w};
            s16x8 ph, pl;
            split8(vv, ph, pl);
            const int s = kg >> 2, g = kg & 3, l = g * 16 + lr;
            const int off = (((c * 2 + s) * 4 + nt) << 10) + l * 16;  // FRAG(c,s,nt) + lane*16
            *(s16x8*)(whi + off) = ph;
            *(s16x8*)(wlo + off) = pl;
        }
    }
}

// ---------------- k_argmin: 4 waves x disjoint 32-row tiles, software-pipelined score loop
template<bool PRE>
__global__ __launch_bounds__(256, 3) void k_argmin(
    const float* __restrict__ x, const float* __restrict__ w,
    float* __restrict__ ws, float* __restrict__ out)
{
    __shared__ __align__(16) float xs[8192];          // 32 KB swizzled x-tile (128 rows)
    __shared__ __align__(16) float redw[2][4][64];    // 2 KB vq wave-partials
    __shared__ float fb1[128], fb2[128];
    __shared__ int   ridx[128];
    __shared__ int   ulist[128];
    __shared__ int   nunc;

    const int t = threadIdx.x;
    const int l = t & 63, wid = t >> 6;               // 4 waves
    const int g = l >> 4, lr = l & 15;
    const long brow = (long)blockIdx.x * 128;
    const float* wn_g = ws + WN_OFF;
    const char* whi = (const char*)ws + WBF_BYTE;
    const char* wlo = whi + 65536;

    if (t == 0) nunc = 0;

    // ---- software pipeline state
    s16x8 pbh[2][4], pbl[2][4];
    float4 pv0[2][4], pv1[2][4];
    f32x4 acc[2][4];

    auto issue = [&](int h, int par) {
        const int c = h >> 1, half = h & 1;
#pragma unroll
        for (int s = 0; s < 2; ++s)
#pragma unroll
            for (int nth = 0; nth < 2; ++nth) {
                const int nt = half * 2 + nth, idx = s * 2 + nth;
                if constexpr (PRE) {
                    const int off = (((c * 2 + s) * 4 + nt) << 10) + l * 16;
                    pbh[par][idx] = *(const s16x8*)(whi + off);
                    pbl[par][idx] = *(const s16x8*)(wlo + off);
                } else {
                    const int crow = c * 64 + nt * 16 + lr;
                    const float* src = w + (long)crow * 64 + (s * 4 + g) * 8;
                    pv0[par][idx] = *(const float4*)src;
                    pv1[par][idx] = *(const float4*)(src + 4);
                }
            }
    };

    issue(0, 0);    // first B-loads fly under the x staging below (no LDS dependence)

    // ---- stage x-tile (coalesced 1KB wave-runs -> swizzled LDS)
#pragma unroll
    for (int ii = 0; ii < 8; ++ii) {
        const int gid = ii * 256 + t;
        const int r = gid >> 4, qq = gid & 15;
        const float4 v = *(const float4*)(x + (brow + r) * 64 + qq * 4);
        *(float4*)((char*)xs + xs_byte(r, qq)) = v;
    }
    __syncthreads();

    // ---- A fragments for this wave's 32 rows (convert ONCE per wave)
    s16x8 ah[2][2], al[2][2];
#pragma unroll
    for (int mt = 0; mt < 2; ++mt) {
        const int row = wid * 32 + mt * 16 + lr;
#pragma unroll
        for (int s = 0; s < 2; ++s) {
            const int kg = s * 4 + g;
            const float4 v0 = *(const float4*)((const char*)xs + xs_byte(row, kg * 2));
            const float4 v1 = *(const float4*)((const char*)xs + xs_byte(row, kg * 2 + 1));
            const float vv[8] = {v0.x, v0.y, v0.z, v0.w, v1.x, v1.y, v1.z, v1.w};
            split8(vv, ah[mt][s], al[mt][s]);
        }
    }

    float b1[2][4], b2[2][4]; int i1[2][4];
#pragma unroll
    for (int mt = 0; mt < 2; ++mt)
#pragma unroll
        for (int j = 0; j < 4; ++j) { b1[mt][j] = 3.4e38f; b2[mt][j] = 3.4e38f; i1[mt][j] = 0; }

    auto compute = [&](int h, int par) {
        const int c = h >> 1, half = h & 1;
        if (half == 0) {
            const f32x4 z = {0.f, 0.f, 0.f, 0.f};
#pragma unroll
            for (int mt = 0; mt < 2; ++mt)
#pragma unroll
                for (int nt = 0; nt < 4; ++nt) acc[mt][nt] = z;
        }
#pragma unroll
        for (int s = 0; s < 2; ++s)
#pragma unroll
            for (int nth = 0; nth < 2; ++nth) {
                const int nt = half * 2 + nth, idx = s * 2 + nth;
                s16x8 BH, BL;
                if constexpr (PRE) {
                    BH = pbh[par][idx]; BL = pbl[par][idx];
                } else {
                    const float4 v0 = pv0[par][idx], v1 = pv1[par][idx];
                    const float vv[8] = {v0.x, v0.y, v0.z, v0.w, v1.x, v1.y, v1.z, v1.w};
                    split8(vv, BH, BL);
                }
#pragma unroll
                for (int mt = 0; mt < 2; ++mt) {
                    acc[mt][nt] = __builtin_amdgcn_mfma_f32_16x16x32_bf16(ah[mt][s], BH, acc[mt][nt], 0, 0, 0);
                    acc[mt][nt] = __builtin_amdgcn_mfma_f32_16x16x32_bf16(al[mt][s], BH, acc[mt][nt], 0, 0, 0);
                    acc[mt][nt] = __builtin_amdgcn_mfma_f32_16x16x32_bf16(ah[mt][s], BL, acc[mt][nt], 0, 0, 0);
                }
            }
        if (half == 1) {   // chunk c complete: selection (codes ascending; strict <)
#pragma unroll
            for (int nt = 0; nt < 4; ++nt) {
                const int code = c * 64 + nt * 16 + lr;
                const float wnv = wn_g[code];
#pragma unroll
                for (int mt = 0; mt < 2; ++mt)
#pragma unroll
                    for (int j = 0; j < 4; ++j) {
                        const float sv = fmaf(-2.f, acc[mt][nt][j], wnv);
                        if (sv < b1[mt][j]) { b2[mt][j] = b1[mt][j]; b1[mt][j] = sv; i1[mt][j] = code; }
                        else if (sv < b2[mt][j]) b2[mt][j] = sv;
                    }
            }
        }
    };

#pragma unroll
    for (int h = 0; h < 16; ++h) {
        if (h < 15) issue(h + 1, (h + 1) & 1);   // loads for next half fly under this half's MFMAs
        compute(h, h & 1);
    }

    // ---- cross-lane merge over 16 code-columns (masks 1,2,4,8), best + 2nd
#pragma unroll
    for (int m = 1; m < 16; m <<= 1) {
#pragma unroll
        for (int mt = 0; mt < 2; ++mt)
#pragma unroll
            for (int j = 0; j < 4; ++j) {
                const float ov1 = __shfl_xor(b1[mt][j], m, 64);
                const int   oi1 = __shfl_xor(i1[mt][j], m, 64);
                const float ov2 = __shfl_xor(b2[mt][j], m, 64);
                const float nb2 = fminf(fminf(b2[mt][j], ov2), fmaxf(b1[mt][j], ov1));
                if (ov1 < b1[mt][j] || (ov1 == b1[mt][j] && oi1 < i1[mt][j])) {
                    b1[mt][j] = ov1; i1[mt][j] = oi1;
                }
                b2[mt][j] = nb2;
            }
    }
    if (lr == 0) {
#pragma unroll
        for (int mt = 0; mt < 2; ++mt)
#pragma unroll
            for (int j = 0; j < 4; ++j) {
                const int ro = wid * 32 + mt * 16 + g * 4 + j;
                ridx[ro] = i1[mt][j];
                fb1[ro] = b1[mt][j];
                fb2[ro] = b2[mt][j];
            }
    }
    __syncthreads();

    // ---- winner verification: 2 threads/row, exact fp32 (x from LDS)
    {
        const int r = t >> 1, sub = t & 1;
        const int ci = ridx[r];
        const float* wrow = w + (long)ci * 64 + sub * 32;
        float dot = 0.f;
#pragma unroll
        for (int p = 0; p < 8; ++p) {
            const float4 xv = *(const float4*)((const char*)xs + xs_byte(r, sub * 8 + p));
            const float4 wv = *(const float4*)(wrow + p * 4);
            dot = fmaf(xv.x, wv.x, dot);
            dot = fmaf(xv.y, wv.y, dot);
            dot = fmaf(xv.z, wv.z, dot);
            dot = fmaf(xv.w, wv.w, dot);
        }
        dot += __shfl_xor(dot, 1, 64);
        if (sub == 0) {
            const float sex = fmaf(-2.f, dot, wn_g[ci]);
            const bool unc = ((fb2[r] - fb1[r]) < TAU) || (fabsf(sex - fb1[r]) > CHK);
            if (unc) { const int p = atomicAdd(&nunc, 1); ulist[p] = r; }
        }
    }
    __syncthreads();

    // ---- in-block exact fix: one wave per marked row (x broadcast from LDS)
    const int nu = nunc;
    if (nu > 0) {
        for (int e = wid; e < nu; e += 4) {
            const int r = ulist[e];
            float bv = 3.4e38f; int bi = 0;
            for (int cc = 0; cc < 8; ++cc) {
                const int code = cc * 64 + l;
                const float* wrow = w + (long)code * 64;
                float dot = 0.f;
#pragma unroll
                for (int p = 0; p < 16; ++p) {
                    const float4 xv = *(const float4*)((const char*)xs + xs_byte(r, p));
                    const float4 wv = *(const float4*)(wrow + p * 4);
                    dot = fmaf(xv.x, wv.x, dot);
                    dot = fmaf(xv.y, wv.y, dot);
                    dot = fmaf(xv.z, wv.z, dot);
                    dot = fmaf(xv.w, wv.w, dot);
                }
                const float sv = fmaf(-2.f, dot, wn_g[code]);
                if (sv < bv) { bv = sv; bi = code; }
            }
#pragma unroll
            for (int m = 1; m < 64; m <<= 1) {
                const float ov = __shfl_xor(bv, m, 64);
                const int   oi = __shfl_xor(bi, m, 64);
                if (ov < bv || (ov == bv && oi < bi)) { bv = ov; bi = oi; }
            }
            if (l == 0) ridx[r] = bi;
        }
    }
    __syncthreads();

    // ---- epilogue: gather w rows -> q_sg, q (nontemporal); vq diff^4 partials
    float* q_sg = out + 5;
    float* q    = out + 5 + (long)M_ * 64;
    float* fidx = out + 5 + 2L * M_ * 64;
    const int qq = t & 15, ry = t >> 4;
    float4 va = {0.f, 0.f, 0.f, 0.f}, vb = {0.f, 0.f, 0.f, 0.f};
#pragma unroll
    for (int ii = 0; ii < 8; ++ii) {
        const int r = ii * 16 + ry;                   // ii<4 -> n0 rows, ii>=4 -> n1
        const int ci = ridx[r];
        const float4 wv4 = *(const float4*)(w + (long)ci * 64 + qq * 4);
        const float4 xv4 = *(const float4*)((const char*)xs + xs_byte(r, qq));
        const long off = (brow + r) * 64 + qq * 4;
        nt_store4(q_sg + off, wv4.x, wv4.y, wv4.z, wv4.w);
        nt_store4(q + off,    wv4.x, wv4.y, wv4.z, wv4.w);
        float4 p;
        p.x = (wv4.x - xv4.x) * (wv4.x - xv4.x);
        p.y = (wv4.y - xv4.y) * (wv4.y - xv4.y);
        p.z = (wv4.z - xv4.z) * (wv4.z - xv4.z);
        p.w = (wv4.w - xv4.w) * (wv4.w - xv4.w);
        float4 p2;
        p2.x = p.x * p.x; p2.y = p.y * p.y; p2.z = p.z * p.z; p2.w = p.w * p.w;
        if (ii < 4) {
            va.x += p2.x; va.y += p2.y; va.z += p2.z; va.w += p2.w;
        } else {
            vb.x += p2.x; vb.y += p2.y; vb.z += p2.z; vb.w += p2.w;
        }
    }
    // wave-local reduce over the wave's 4 ry values (lanes l, l^16, l^32 share qq)
#pragma unroll
    for (int m = 16; m < 64; m <<= 1) {
        va.x += __shfl_xor(va.x, m, 64); va.y += __shfl_xor(va.y, m, 64);
        va.z += __shfl_xor(va.z, m, 64); va.w += __shfl_xor(va.w, m, 64);
        vb.x += __shfl_xor(vb.x, m, 64); vb.y += __shfl_xor(vb.y, m, 64);
        vb.z += __shfl_xor(vb.z, m, 64); vb.w += __shfl_xor(vb.w, m, 64);
    }
    if (l < 16) {
        *(float4*)&redw[0][wid][l * 4] = va;
        *(float4*)&redw[1][wid][l * 4] = vb;
    }
    if (t < 128) __builtin_nontemporal_store((float)ridx[t], fidx + brow + t);
    __syncthreads();

    // ---- vq finish: per (n, d) sums over 4 wave-partials, sqrt, sum over d
    if (t < 128) {
        const int n = t >> 6, d = t & 63;
        const float s = redw[n][0][d] + redw[n][1][d] + redw[n][2][d] + redw[n][3][d];
        float v = sqrtf(s);
#pragma unroll
        for (int m = 1; m < 64; m <<= 1) v += __shfl_xor(v, m, 64);
        if (d == 0) atomicAdd(ws + 0, v);
    }
}

// ---------------- k_final: orth from gram, rank via Gaussian elimination (1 barrier/step)
__global__ void k_final(const float* __restrict__ ws, float* __restrict__ out)
{
    __shared__ float g[64][65];
    __shared__ float osum[4];
    __shared__ float tol;
    const int t = threadIdx.x;
    float oacc = 0.f;
    for (int i = t; i < 4096; i += 256) {
        const int r = i >> 6, cl = i & 63;
        const float gv = ws[GRAM_OFF + i];
        g[r][cl] = gv;
        const float p = gv - (r == cl ? 1.f : 0.f);
        oacc = fmaf(p, p, oacc);
    }
#pragma unroll
    for (int m = 1; m < 64; m <<= 1) oacc += __shfl_xor(oacc, m, 64);
    if ((t & 63) == 0) osum[t >> 6] = oacc;
    __syncthreads();

    if (t == 0) {
        float maxd = 0.f;
        for (int i = 0; i < 64; ++i) maxd = fmaxf(maxd, fabsf(g[i][i]));
        tol = maxd * 1e-7f + 1e-30f;
    }
    __syncthreads();

    // One barrier per step: within step s, reads hit only row s / col s / diag,
    // writes hit only (r>s, j>s) — disjoint, so no mid-step barrier needed.
    int rank = 0;
    const int j = t & 63, rq = t >> 6;
    for (int s = 0; s < 64; ++s) {
        const float p = g[s][s];
        const bool ok = fabsf(p) > tol;
        if (ok) {
            rank++;
            if (j > s) {
                const float rp = 1.f / p;
                const float gsj = g[s][j];
                for (int r = s + 1 + rq; r < 64; r += 4)
                    g[r][j] = fmaf(-(g[r][s] * rp), gsj, g[r][j]);
            }
        }
        __syncthreads();
    }

    if (t == 0) {
        const float vq = ws[0] / (float)(N_ * D_);
        const float orth = sqrtf(osum[0] + osum[1] + osum[2] + osum[3]);
        out[0] = 1.5f * vq;
        out[1] = vq;
        out[2] = vq;
        out[3] = orth;
        out[4] = (float)rank;
    }
}

// ---------------- launcher
extern "C" void kernel_launch(void* const* d_in, const int* in_sizes, int n_in,
                              void* d_out, int out_size, void* d_ws, size_t ws_size,
                              hipStream_t stream) {
    const float* x = (const float*)d_in[0];   // soft_fillers [N,R,D]
    const float* w = (const float*)d_in[1];   // weight [K,D]
    float* out = (float*)d_out;
    float* ws  = (float*)d_ws;
    const int pre = (ws_size >= (size_t)WS_NEED) ? 1 : 0;

    hipLaunchKernelGGL(k_pre, dim3(68), dim3(256), 0, stream, w, ws, pre);
    if (pre)
        hipLaunchKernelGGL((k_argmin<true>),  dim3(1024), dim3(256), 0, stream, x, w, ws, out);
    else
        hipLaunchKernelGGL((k_argmin<false>), dim3(1024), dim3(256), 0, stream, x, w, ws, out);
    hipLaunchKernelGGL(k_final, dim3(1), dim3(256), 0, stream, ws, out);
}